// Round 1
// 5002.377 us; speedup vs baseline: 1.2303x; 1.2303x over previous
//
#include <hip/hip_runtime.h>
#include <math.h>

#define BSZ 64
#define PLEN 128
#define HLEN 64
#define EDIM 300
#define HDIM 512
#define G4 2048   // 4*HDIM
#define NCLS 3

__device__ __forceinline__ float sigf(float x) { return 1.0f / (1.0f + __expf(-x)); }
__device__ __forceinline__ float tanhfast(float x) { return 1.0f - 2.0f / (__expf(2.0f * x) + 1.0f); }

// relaxed agent-scope atomic helpers: LLC-coherent, no L2 flush/invalidate
__device__ __forceinline__ unsigned long long aload64(const unsigned long long* p) {
    return __hip_atomic_load(p, __ATOMIC_RELAXED, __HIP_MEMORY_SCOPE_AGENT);
}
__device__ __forceinline__ void astore64(unsigned long long* p, unsigned long long v) {
    __hip_atomic_store(p, v, __ATOMIC_RELAXED, __HIP_MEMORY_SCOPE_AGENT);
}
__device__ __forceinline__ void astore32(float* p, float v) {
    __hip_atomic_store(p, v, __ATOMIC_RELAXED, __HIP_MEMORY_SCOPE_AGENT);
}

__global__ __launch_bounds__(256) void flag_init(unsigned* f) {
    f[blockIdx.x * 256 + threadIdx.x] = 0u;
}

// ---------------------------------------------------------------------------
// input projection GEMM: out[m][row] = emb[toks[m]] . Wih[row] + bih[row]+bhh[row]
__global__ __launch_bounds__(256) void proj_kernel(
    const int* __restrict__ toks, const float* __restrict__ emb,
    const float* __restrict__ Wih, const float* __restrict__ bih,
    const float* __restrict__ bhh, float* __restrict__ out)
{
    __shared__ float es[16][EDIM];
    __shared__ float wsh[32][EDIM];
    int m0 = blockIdx.x * 16, r0 = blockIdx.y * 32;
    int tid = threadIdx.x;
    for (int i = tid; i < 16 * 75; i += 256) {
        int tk = i / 75, k4 = i % 75;
        ((float4*)&es[tk][0])[k4] = ((const float4*)(emb + (size_t)toks[m0 + tk] * EDIM))[k4];
    }
    for (int i = tid; i < 32 * 75; i += 256) {
        int r = i / 75, k4 = i % 75;
        ((float4*)&wsh[r][0])[k4] = ((const float4*)(Wih + (size_t)(r0 + r) * EDIM))[k4];
    }
    __syncthreads();
    int tx = tid & 31, ty = tid >> 5;
    const float4* w4 = (const float4*)&wsh[tx][0];
    const float4* e0 = (const float4*)&es[ty][0];
    const float4* e1 = (const float4*)&es[ty + 8][0];
    float a0 = 0.f, a1 = 0.f;
#pragma unroll 5
    for (int k = 0; k < 75; k++) {
        float4 w = w4[k];
        float4 x = e0[k]; a0 += x.x * w.x + x.y * w.y + x.z * w.z + x.w * w.w;
        float4 y = e1[k]; a1 += y.x * w.x + y.y * w.y + y.z * w.z + y.w * w.w;
    }
    float bsum = bih[r0 + tx] + bhh[r0 + tx];
    out[(size_t)(m0 + ty) * G4 + r0 + tx]     = a0 + bsum;
    out[(size_t)(m0 + ty + 8) * G4 + r0 + tx] = a1 + bsum;
}

// ---------------------------------------------------------------------------
// persistent LSTM, flag-synced within batch-groups. 256 blocks x 256 threads.
// block = (ug 0..31, bg 0..7): units u0..u0+15, batches b0..b0+7.
// 64 gate-row weights live in VGPRs (thread (r,c): row r chunk c of 128).
__global__ __launch_bounds__(256, 1) void lstm_coop(
    const float* __restrict__ xp, const float* __restrict__ xh,
    const float* __restrict__ Whh1, const float* __restrict__ Whh2,
    float* __restrict__ outp, float* __restrict__ outh,
    float* __restrict__ hA, float* __restrict__ hB,
    unsigned* __restrict__ flags)
{
    const int tid = threadIdx.x;
    const int ug = blockIdx.x & 31;
    const int bg = blockIdx.x >> 5;
    const int u0 = ug * 16, b0 = bg * 8;
    const int r = tid >> 2, c = tid & 3;   // r 0..63 = g*16+uu
    const int g = r >> 4, uur = r & 15;

    __shared__ float hst[8][516];
    __shared__ float gsm[64][9];

    float4 w[32];
    {
        const float4* src = (const float4*)(Whh1 + ((size_t)(g * HDIM + u0 + uur)) * HDIM) + c * 32;
#pragma unroll
        for (int k = 0; k < 32; k++) w[k] = src[k];
    }
    float creg = 0.0f;                       // cell state, thread-private (tid<128)
    const int bbc = tid >> 4, uuc = tid & 15;
    unsigned* myflags = flags + bg * 192;

    for (int t = 0; t < PLEN + HLEN; t++) {
        const int layer2 = (t >= PLEN) ? 1 : 0;
        const int tloc = layer2 ? t - PLEN : t;
        const int T = layer2 ? HLEN : PLEN;
        const float* xproj = layer2 ? xh : xp;
        float* outseq = layer2 ? outh : outp;
        float* hwr = (t & 1) ? hB : hA;
        const float* hrd = (t & 1) ? hA : hB;

        if (t == PLEN) {   // reload layer-2 weights into VGPRs (uniform)
            const float4* src = (const float4*)(Whh2 + ((size_t)(g * HDIM + u0 + uur)) * HDIM) + c * 32;
#pragma unroll
            for (int k = 0; k < 32; k++) w[k] = src[k];
        }
        const bool have_h = (tloc != 0);
        if (have_h) {
            // wait: all 32 u-groups of this b-group stored h_{t-1}
            if (tid == 0) {
                while (__hip_atomic_load(&myflags[t - 1], __ATOMIC_RELAXED,
                                         __HIP_MEMORY_SCOPE_AGENT) != 32u)
                    __builtin_amdgcn_s_sleep(1);
            }
            __syncthreads();
            __asm__ volatile("" ::: "memory");
            // stage h_{t-1} (8 batches x 512) via LLC-coherent u64 loads
            const unsigned long long* hs64 =
                (const unsigned long long*)(hrd) + (size_t)b0 * 256;
#pragma unroll
            for (int i = 0; i < 8; i++) {
                int idx = tid + i * 256;
                int bb = idx >> 8, j = idx & 255;
                unsigned long long v = aload64(hs64 + bb * 256 + j);
                *(unsigned long long*)&hst[bb][j * 2] = v;
            }
            __syncthreads();
            // GEMV: gate row r, chunk c (weights in VGPRs, h broadcast from LDS)
#pragma unroll 1
            for (int bb = 0; bb < 8; bb++) {
                const float4* hv = (const float4*)&hst[bb][0] + c * 32;
                float ax = 0.f, ay = 0.f, az = 0.f, aw = 0.f;
#pragma unroll
                for (int k = 0; k < 32; k++) {
                    float4 a = w[k], x = hv[k];
                    ax += a.x * x.x; ay += a.y * x.y; az += a.z * x.z; aw += a.w * x.w;
                }
                float acc = (ax + ay) + (az + aw);
                acc += __shfl_xor(acc, 1);
                acc += __shfl_xor(acc, 2);
                if (c == 0) gsm[r][bb] = acc;
            }
        }
        __syncthreads();
        // cell update: thread (bb, uu), tid<128
        if (tid < 128) {
            const int b = b0 + bbc;
            size_t xb = ((size_t)b * T + tloc) * G4 + u0 + uuc;
            float gi = xproj[xb], gf = xproj[xb + 512];
            float gg = xproj[xb + 1024], go = xproj[xb + 1536];
            if (have_h) {
                gi += gsm[uuc][bbc];
                gf += gsm[16 + uuc][bbc];
                gg += gsm[32 + uuc][bbc];
                go += gsm[48 + uuc][bbc];
            }
            float cn = sigf(gf) * creg + sigf(gi) * tanhfast(gg);
            float hn = sigf(go) * tanhfast(cn);
            creg = cn;
            outseq[((size_t)b * T + tloc) * HDIM + u0 + uuc] = hn;
            float pr = __shfl_xor(hn, 1);
            if ((uuc & 1) == 0) {
                float2 v2 = make_float2(hn, pr);
                astore64((unsigned long long*)(hwr + (size_t)b * HDIM + u0 + uuc),
                         *(unsigned long long*)&v2);
            }
        }
        __asm__ volatile("" ::: "memory");
        __builtin_amdgcn_s_waitcnt(0);   // h stores complete at LLC
        __syncthreads();
        if (tid == 0)
            __hip_atomic_fetch_add(&myflags[t], 1u, __ATOMIC_RELAXED,
                                   __HIP_MEMORY_SCOPE_AGENT);
    }
}

// ---------------------------------------------------------------------------
// a1t[b][p][h] = sum_j Wy[h][j] * outp[b][p][j]   (TRANSPOSED layout: [b][p][h])
__global__ __launch_bounds__(256) void a1_kernel(
    const float* __restrict__ Wy, const float* __restrict__ outp,
    float* __restrict__ a1t)
{
    __shared__ float os[16][260];
    __shared__ float wsh[16][260];
    int b = blockIdx.x, h0 = blockIdx.y * 16, p0 = blockIdx.z * 16;
    int tid = threadIdx.x, tx = tid & 15, ty = tid >> 4;
    float acc = 0.f;
    for (int kc = 0; kc < 2; kc++) {
        __syncthreads();
        for (int i = tid; i < 16 * 64; i += 256) {
            int row = i >> 6, k4 = i & 63;
            ((float4*)&os[row][0])[k4] =
                ((const float4*)(outp + (size_t)(b * PLEN + p0 + row) * HDIM + kc * 256))[k4];
            ((float4*)&wsh[row][0])[k4] =
                ((const float4*)(Wy + (size_t)(h0 + row) * HDIM + kc * 256))[k4];
        }
        __syncthreads();
        const float4* ov = (const float4*)&os[ty][0];    // p = p0+ty
        const float4* wv4 = (const float4*)&wsh[tx][0];  // h = h0+tx
#pragma unroll 8
        for (int k = 0; k < 64; k++) {
            float4 a = ov[k], w = wv4[k];
            acc += a.x * w.x + a.y * w.y + a.z * w.z + a.w * w.w;
        }
    }
    // coalesced in h (16 consecutive floats per p-row)
    a1t[((size_t)b * PLEN + p0 + ty) * HDIM + h0 + tx] = acc;
}

// ---------------------------------------------------------------------------
// persistent attention, flag-synced within batch-groups. 256 blocks x 256 thr.
// block = (ug, bg): 16 units (phases A/C), 4 premise positions (phase B), 8 batches.
// 48 weight rows (Wh/Wr/Wt x 16 units) in VGPRs of threads r<48.
// a1 slice (8b x 4p x 512h) lives in VGPRs (16 float4/thread), loaded ONCE.
// outp slice (8b x 128p x 16u) lives in LDS, loaded ONCE.
#define OSTR 2056   // 128*16 + 8 pad: phase-C gather lands 2-way max
__global__ __launch_bounds__(256, 1) void att_coop(
    const float* __restrict__ outh, const float* __restrict__ a1b,
    const float* __restrict__ outp,
    const float* __restrict__ Wh, const float* __restrict__ Wr,
    const float* __restrict__ Wt, const float* __restrict__ wv,
    float* __restrict__ a2buf, float* __restrict__ sbuf,
    float* __restrict__ rA, float* __restrict__ rB,
    unsigned* __restrict__ flags)
{
    const int tid = threadIdx.x;
    const int ug = blockIdx.x & 31;
    const int bg = blockIdx.x >> 5;
    const int u0 = ug * 16, b0 = bg * 8;
    const int r = tid >> 2, c = tid & 3;   // r<48: m = r>>4 (0:Wh 1:Wr 2:Wt), uu = r&15
    const int m = r >> 4, uur = r & 15;

    __shared__ __align__(16) float ops[8 * OSTR];   // persistent outp slice
    __shared__ __align__(16) float qa[8][516];      // phase A: q_t ; phase B: a2 (aliased)
    __shared__ __align__(16) float rst[8][516];
    __shared__ __align__(16) float scst[8][132];
    __shared__ float dsm[48][9];
    __shared__ float tts[16][9];
    __shared__ __align__(16) float wvs[512];

    float4 w[32];
    if (r < 48) {
        const float* W = (m == 0) ? Wh : ((m == 1) ? Wr : Wt);
        const float4* src = (const float4*)(W + (size_t)(u0 + uur) * HDIM) + c * 32;
#pragma unroll
        for (int k = 0; k < 32; k++) w[k] = src[k];
    }
    for (int i = tid; i < 128; i += 256)
        ((float4*)wvs)[i] = ((const float4*)wv)[i];

    // ---- one-time: outp slice -> LDS (64 KB, reused by all 64 steps)
    for (int i = tid; i < 8 * 128 * 4; i += 256) {
        int bb = i >> 9;
        int rem = i & 511;
        int p = rem >> 2, q = rem & 3;
        float4 v = *((const float4*)(outp + ((size_t)(b0 + bb) * PLEN + p) * HDIM + u0) + q);
        *((float4*)(ops + bb * OSTR + p * 16) + q) = v;
    }

    // ---- one-time: a1 slice -> VGPRs (16 float4/thread, coalesced)
    const int wvid = tid >> 6, lane = tid & 63;
    const int p0g = ug * 4;
    float4 a1r[8][2];
#pragma unroll
    for (int i = 0; i < 8; i++) {
        int pr = wvid * 8 + i;
        int bb = pr >> 2, pp = pr & 3;
        const float4* src = (const float4*)(a1b + ((size_t)(b0 + bb) * PLEN + p0g + pp) * HDIM) + lane;
        a1r[i][0] = src[0];
        a1r[i][1] = src[64];
    }

    unsigned* fA = flags + 1536 + bg * 64;
    unsigned* fB = flags + 1536 + 512 + bg * 64;
    unsigned* fC = flags + 1536 + 1024 + bg * 64;
    const int bbc = tid >> 4, uuc = tid & 15;

    for (int t = 0; t < HLEN; t++) {
        float* rwr = (t & 1) ? rB : rA;
        const float* rrd = (t & 1) ? rA : rB;

        // ---- phase A: a2 = q.Wh + r.Wr ; tt = tanh(r.Wt)
        if (t > 0 && tid == 0) {
            while (__hip_atomic_load(&fC[t - 1], __ATOMIC_RELAXED,
                                     __HIP_MEMORY_SCOPE_AGENT) != 32u)
                __builtin_amdgcn_s_sleep(1);
        }
        __syncthreads();
        __asm__ volatile("" ::: "memory");
        for (int i = tid; i < 8 * 128; i += 256) {
            int bb = i >> 7, k4 = i & 127;
            ((float4*)&qa[bb][0])[k4] =
                ((const float4*)(outh + ((size_t)(b0 + bb) * HLEN + t) * HDIM))[k4];
        }
        if (t > 0) {
            const unsigned long long* rs64 =
                (const unsigned long long*)(rrd) + (size_t)b0 * 256;
#pragma unroll
            for (int i = 0; i < 8; i++) {
                int idx = tid + i * 256;
                int bb = idx >> 8, j = idx & 255;
                *(unsigned long long*)&rst[bb][j * 2] = aload64(rs64 + bb * 256 + j);
            }
        }
        __syncthreads();
        if (r < 48 && (t > 0 || m == 0)) {
#pragma unroll 1
            for (int bb = 0; bb < 8; bb++) {
                const float4* sv = (const float4*)((m == 0) ? &qa[bb][0] : &rst[bb][0]) + c * 32;
                float ax = 0.f, ay = 0.f, az = 0.f, aw = 0.f;
#pragma unroll
                for (int k = 0; k < 32; k++) {
                    float4 a = w[k], x = sv[k];
                    ax += a.x * x.x; ay += a.y * x.y; az += a.z * x.z; aw += a.w * x.w;
                }
                float acc = (ax + ay) + (az + aw);
                acc += __shfl_xor(acc, 1);
                acc += __shfl_xor(acc, 2);
                if (c == 0) dsm[r][bb] = acc;
            }
        }
        __syncthreads();
        if (tid < 128) {
            float aq = dsm[uuc][bbc];
            float ar = (t > 0) ? dsm[16 + uuc][bbc] : 0.0f;
            float at = (t > 0) ? dsm[32 + uuc][bbc] : 0.0f;
            float a2v = aq + ar;
            tts[uuc][bbc] = (t > 0) ? tanhfast(at) : 0.0f;
            float pr = __shfl_xor(a2v, 1);
            if ((uuc & 1) == 0) {
                float2 v2 = make_float2(a2v, pr);
                astore64((unsigned long long*)(a2buf + (size_t)(b0 + bbc) * HDIM + u0 + uuc),
                         *(unsigned long long*)&v2);
            }
        }
        __asm__ volatile("" ::: "memory");
        __builtin_amdgcn_s_waitcnt(0);
        __syncthreads();
        if (tid == 0)
            __hip_atomic_fetch_add(&fA[t], 1u, __ATOMIC_RELAXED, __HIP_MEMORY_SCOPE_AGENT);

        // ---- phase B: s[b][p-slice] = sum_h wv[h]*tanh(a1 + a2)
        // a1 is in VGPRs; a2 staged into qa (aliases dead q_t); conflict-free b128 reads.
        if (tid == 0) {
            while (__hip_atomic_load(&fA[t], __ATOMIC_RELAXED,
                                     __HIP_MEMORY_SCOPE_AGENT) != 32u)
                __builtin_amdgcn_s_sleep(1);
        }
        __syncthreads();
        __asm__ volatile("" ::: "memory");
        {
            const unsigned long long* a64 =
                (const unsigned long long*)(a2buf) + (size_t)b0 * 256;
#pragma unroll
            for (int i = 0; i < 8; i++) {
                int idx = tid + i * 256;
                int bb = idx >> 8, j = idx & 255;
                *(unsigned long long*)&qa[bb][j * 2] = aload64(a64 + bb * 256 + j);
            }
        }
        __syncthreads();
        {
#pragma unroll 2
            for (int i = 0; i < 8; i++) {
                int pr = wvid * 8 + i;
                int bb = pr >> 2, pp = pr & 3;
                float s = 0.f;
#pragma unroll
                for (int k = 0; k < 2; k++) {
                    float4 av = a1r[i][k];
                    float4 a2v = *((const float4*)&qa[bb][0] + lane + 64 * k);
                    float4 wv4 = *((const float4*)wvs + lane + 64 * k);
                    s += wv4.x * tanhfast(av.x + a2v.x)
                       + wv4.y * tanhfast(av.y + a2v.y)
                       + wv4.z * tanhfast(av.z + a2v.z)
                       + wv4.w * tanhfast(av.w + a2v.w);
                }
#pragma unroll
                for (int o = 1; o < 64; o <<= 1) s += __shfl_xor(s, o);
                if (lane == 0)
                    astore32(sbuf + (size_t)(b0 + bb) * PLEN + p0g + pp, s);
            }
        }
        __asm__ volatile("" ::: "memory");
        __builtin_amdgcn_s_waitcnt(0);
        __syncthreads();
        if (tid == 0)
            __hip_atomic_fetch_add(&fB[t], 1u, __ATOMIC_RELAXED, __HIP_MEMORY_SCOPE_AGENT);

        // ---- phase C: softmax over p (redundant per block) + r update from LDS-resident outp
        if (tid == 0) {
            while (__hip_atomic_load(&fB[t], __ATOMIC_RELAXED,
                                     __HIP_MEMORY_SCOPE_AGENT) != 32u)
                __builtin_amdgcn_s_sleep(1);
        }
        __syncthreads();
        __asm__ volatile("" ::: "memory");
        {
            const unsigned long long* s64 =
                (const unsigned long long*)(sbuf) + (size_t)b0 * 64;
#pragma unroll
            for (int i = 0; i < 2; i++) {
                int idx = tid + i * 256;
                int bb = idx >> 6, j = idx & 63;
                *(unsigned long long*)&scst[bb][j * 2] = aload64(s64 + bb * 64 + j);
            }
        }
        __syncthreads();
        {
            const int bb = tid >> 5, j = tid & 31;
            float4 v = *(float4*)&scst[bb][j * 4];
            float mx = fmaxf(fmaxf(v.x, v.y), fmaxf(v.z, v.w));
#pragma unroll
            for (int o = 1; o < 32; o <<= 1) mx = fmaxf(mx, __shfl_xor(mx, o));
            float ex = __expf(v.x - mx), ey = __expf(v.y - mx);
            float ez = __expf(v.z - mx), ew = __expf(v.w - mx);
            float ssum = (ex + ey) + (ez + ew);
#pragma unroll
            for (int o = 1; o < 32; o <<= 1) ssum += __shfl_xor(ssum, o);
            float inv = 1.0f / ssum;
            float4 sc4 = make_float4(ex * inv, ey * inv, ez * inv, ew * inv);
            *(float4*)&scst[bb][j * 4] = sc4;
        }
        __syncthreads();
        if (tid < 128) {
            float acc = tts[uuc][bbc];
            const float* opb = ops + bbc * OSTR + uuc;
#pragma unroll 8
            for (int p = 0; p < PLEN; p++)
                acc += scst[bbc][p] * opb[p * 16];
            float pr = __shfl_xor(acc, 1);
            if ((uuc & 1) == 0) {
                float2 v2 = make_float2(acc, pr);
                astore64((unsigned long long*)(rwr + (size_t)(b0 + bbc) * HDIM + u0 + uuc),
                         *(unsigned long long*)&v2);
            }
        }
        __asm__ volatile("" ::: "memory");
        __builtin_amdgcn_s_waitcnt(0);
        __syncthreads();
        if (tid == 0)
            __hip_atomic_fetch_add(&fC[t], 1u, __ATOMIC_RELAXED, __HIP_MEMORY_SCOPE_AGENT);
    }
}

// ---------------------------------------------------------------------------
// final: rep = tanh(r.fc1^T + b1 + hn.fc2^T + b2); out = rep.fc3^T + b3
__global__ __launch_bounds__(256) void final_kernel(
    const float* __restrict__ r, const float* __restrict__ outh,
    const float* __restrict__ fc1w, const float* __restrict__ fc1b,
    const float* __restrict__ fc2w, const float* __restrict__ fc2b,
    const float* __restrict__ fc3w, const float* __restrict__ fc3b,
    float* __restrict__ out)
{
    int b = blockIdx.x, tid = threadIdx.x;
    __shared__ float rs[HDIM], hs[HDIM], rep[HDIM], red[256];
    for (int i = tid; i < 128; i += 256) {
        ((float4*)rs)[i] = ((const float4*)(r + (size_t)b * HDIM))[i];
        ((float4*)hs)[i] = ((const float4*)(outh + ((size_t)(b * HLEN + HLEN - 1)) * HDIM))[i];
    }
    __syncthreads();
    for (int u = tid; u < HDIM; u += 256) {
        const float4* w1 = (const float4*)(fc1w + (size_t)u * HDIM);
        const float4* w2 = (const float4*)(fc2w + (size_t)u * HDIM);
        float a = 0.f, bacc = 0.f;
        for (int k = 0; k < 128; k++) {
            float4 rv = ((float4*)rs)[k], hv = ((float4*)hs)[k];
            float4 x = w1[k]; a    += rv.x * x.x + rv.y * x.y + rv.z * x.z + rv.w * x.w;
            float4 y = w2[k]; bacc += hv.x * y.x + hv.y * y.y + hv.z * y.z + hv.w * y.w;
        }
        rep[u] = tanhfast(a + fc1b[u] + bacc + fc2b[u]);
    }
    __syncthreads();
    for (int cix = 0; cix < NCLS; cix++) {
        red[tid] = rep[tid] * fc3w[(size_t)cix * HDIM + tid]
                 + rep[tid + 256] * fc3w[(size_t)cix * HDIM + tid + 256];
        __syncthreads();
        for (int off = 128; off; off >>= 1) {
            if (tid < off) red[tid] += red[tid + off];
            __syncthreads();
        }
        if (tid == 0) out[b * NCLS + cix] = red[0] + fc3b[cix];
        __syncthreads();
    }
}

// ---------------------------------------------------------------------------
extern "C" void kernel_launch(void* const* d_in, const int* in_sizes, int n_in,
                              void* d_out, int out_size, void* d_ws, size_t ws_size,
                              hipStream_t stream)
{
    const int*   premise = (const int*)d_in[0];
    const int*   hyp     = (const int*)d_in[1];
    const float* emb     = (const float*)d_in[2];
    const float* Wih1    = (const float*)d_in[3];
    const float* Whh1    = (const float*)d_in[4];
    const float* bih1    = (const float*)d_in[5];
    const float* bhh1    = (const float*)d_in[6];
    const float* Wih2    = (const float*)d_in[7];
    const float* Whh2    = (const float*)d_in[8];
    const float* bih2    = (const float*)d_in[9];
    const float* bhh2    = (const float*)d_in[10];
    const float* Wy      = (const float*)d_in[11];
    const float* Wh      = (const float*)d_in[12];
    const float* Wr      = (const float*)d_in[13];
    const float* Wt      = (const float*)d_in[14];
    const float* wv      = (const float*)d_in[15];
    const float* fc1w    = (const float*)d_in[16];
    const float* fc1b    = (const float*)d_in[17];
    const float* fc2w    = (const float*)d_in[18];
    const float* fc2b    = (const float*)d_in[19];
    const float* fc3w    = (const float*)d_in[20];
    const float* fc3b    = (const float*)d_in[21];
    float* out = (float*)d_out;

    float* ws = (float*)d_ws;
    size_t off = 0;
    float* xp    = ws + off; off += (size_t)BSZ * PLEN * G4;
    float* xh    = ws + off; off += (size_t)BSZ * HLEN * G4;
    float* outp  = ws + off; off += (size_t)BSZ * PLEN * HDIM;
    float* outhp = ws + off; off += (size_t)BSZ * HLEN * HDIM;
    float* a1b   = ws + off; off += (size_t)BSZ * HDIM * PLEN;   // stored as [b][p][h]
    float* hAb   = ws + off; off += BSZ * HDIM;
    float* hBb   = ws + off; off += BSZ * HDIM;
    float* a2buf = ws + off; off += BSZ * HDIM;
    float* rAb   = ws + off; off += BSZ * HDIM;
    float* rBb   = ws + off; off += BSZ * HDIM;
    float* sbuf  = ws + off; off += BSZ * PLEN;
    unsigned* flags = (unsigned*)(ws + off); off += 4096;
    if (ws_size < off * sizeof(float)) return;

    // zero flag counters every call (d_ws is re-poisoned before each launch)
    flag_init<<<dim3(16), dim3(256), 0, stream>>>(flags);

    // input projections (biases folded in)
    proj_kernel<<<dim3(BSZ * PLEN / 16, G4 / 32), dim3(256), 0, stream>>>(
        premise, emb, Wih1, bih1, bhh1, xp);
    proj_kernel<<<dim3(BSZ * HLEN / 16, G4 / 32), dim3(256), 0, stream>>>(
        hyp, emb, Wih2, bih2, bhh2, xh);

    // both LSTMs, persistent, per-b-group flag sync (no L2-flushing fences)
    lstm_coop<<<dim3(256), dim3(256), 0, stream>>>(
        xp, xh, Whh1, Whh2, outp, outhp, hAb, hBb, flags);

    // a1t = einsum('hj,bpj->bph', Wy, outp)   (transposed: [b][p][h])
    a1_kernel<<<dim3(BSZ, HDIM / 16, PLEN / 16), dim3(256), 0, stream>>>(Wy, outp, a1b);

    // attention recurrence, persistent, per-b-group flag sync
    att_coop<<<dim3(256), dim3(256), 0, stream>>>(
        outhp, a1b, outp, Wh, Wr, Wt, wv, a2buf, sbuf, rAb, rBb, flags);

    // final classifier: r after step 63 lives in rB (63 & 1 == 1)
    final_kernel<<<dim3(BSZ), dim3(256), 0, stream>>>(
        rBb, outhp, fc1w, fc1b, fc2w, fc2b, fc3w, fc3b, out);
}

// Round 2
// 4505.816 us; speedup vs baseline: 1.3658x; 1.1102x over previous
//
#include <hip/hip_runtime.h>
#include <math.h>

#define BSZ 64
#define PLEN 128
#define HLEN 64
#define EDIM 300
#define HDIM 512
#define G4 2048   // 4*HDIM
#define NCLS 3

// chunked 512-float vector layout: 4 chunks of 132 floats (128 data + 4 pad).
// float f (0..511) lives at CH(f) = (f>>7)*132 + (f&127).
// GEMV chunk read c*132+4k -> banks 4c+4k: the 4 c-chunks hit DISTINCT bank
// quads (132%32=4) -> conflict-free broadcast (was 4-way: 512%32=0).
#define CHROW 528
#define CH(f) ((((f) >> 7) * 132) + ((f) & 127))

__device__ __forceinline__ float sigf(float x) { return 1.0f / (1.0f + __expf(-x)); }
__device__ __forceinline__ float tanhfast(float x) { return 1.0f - 2.0f / (__expf(2.0f * x) + 1.0f); }

// relaxed agent-scope atomic helpers: LLC-coherent, no L2 flush/invalidate
__device__ __forceinline__ unsigned long long aload64(const unsigned long long* p) {
    return __hip_atomic_load(p, __ATOMIC_RELAXED, __HIP_MEMORY_SCOPE_AGENT);
}
__device__ __forceinline__ void astore64(unsigned long long* p, unsigned long long v) {
    __hip_atomic_store(p, v, __ATOMIC_RELAXED, __HIP_MEMORY_SCOPE_AGENT);
}
__device__ __forceinline__ void astore32(float* p, float v) {
    __hip_atomic_store(p, v, __ATOMIC_RELAXED, __HIP_MEMORY_SCOPE_AGENT);
}

__global__ __launch_bounds__(256) void flag_init(unsigned* f) {
    f[blockIdx.x * 256 + threadIdx.x] = 0u;
}

// ---------------------------------------------------------------------------
// input projection GEMM: out[m][row] = emb[toks[m]] . Wih[row] + bih[row]+bhh[row]
__global__ __launch_bounds__(256) void proj_kernel(
    const int* __restrict__ toks, const float* __restrict__ emb,
    const float* __restrict__ Wih, const float* __restrict__ bih,
    const float* __restrict__ bhh, float* __restrict__ out)
{
    __shared__ float es[16][EDIM];
    __shared__ float wsh[32][EDIM];
    int m0 = blockIdx.x * 16, r0 = blockIdx.y * 32;
    int tid = threadIdx.x;
    for (int i = tid; i < 16 * 75; i += 256) {
        int tk = i / 75, k4 = i % 75;
        ((float4*)&es[tk][0])[k4] = ((const float4*)(emb + (size_t)toks[m0 + tk] * EDIM))[k4];
    }
    for (int i = tid; i < 32 * 75; i += 256) {
        int r = i / 75, k4 = i % 75;
        ((float4*)&wsh[r][0])[k4] = ((const float4*)(Wih + (size_t)(r0 + r) * EDIM))[k4];
    }
    __syncthreads();
    int tx = tid & 31, ty = tid >> 5;
    const float4* w4 = (const float4*)&wsh[tx][0];
    const float4* e0 = (const float4*)&es[ty][0];
    const float4* e1 = (const float4*)&es[ty + 8][0];
    float a0 = 0.f, a1 = 0.f;
#pragma unroll 5
    for (int k = 0; k < 75; k++) {
        float4 w = w4[k];
        float4 x = e0[k]; a0 += x.x * w.x + x.y * w.y + x.z * w.z + x.w * w.w;
        float4 y = e1[k]; a1 += y.x * w.x + y.y * w.y + y.z * w.z + y.w * w.w;
    }
    float bsum = bih[r0 + tx] + bhh[r0 + tx];
    out[(size_t)(m0 + ty) * G4 + r0 + tx]     = a0 + bsum;
    out[(size_t)(m0 + ty + 8) * G4 + r0 + tx] = a1 + bsum;
}

// ---------------------------------------------------------------------------
// persistent LSTM, flag-synced within batch-groups. 256 blocks x 256 threads.
// block = (ug 0..31, bg 0..7): units u0..u0+15, batches b0..b0+7.
// 64 gate-row weights live in VGPRs (thread (r,c): row r chunk c of 128).
__global__ __launch_bounds__(256, 1) void lstm_coop(
    const float* __restrict__ xp, const float* __restrict__ xh,
    const float* __restrict__ Whh1, const float* __restrict__ Whh2,
    float* __restrict__ outp, float* __restrict__ outh,
    float* __restrict__ hA, float* __restrict__ hB,
    unsigned* __restrict__ flags)
{
    const int tid = threadIdx.x;
    const int ug = blockIdx.x & 31;
    const int bg = blockIdx.x >> 5;
    const int u0 = ug * 16, b0 = bg * 8;
    const int r = tid >> 2, c = tid & 3;   // r 0..63 = g*16+uu
    const int g = r >> 4, uur = r & 15;

    __shared__ __align__(16) float hst[8 * CHROW];   // chunked h staging
    __shared__ float gsm[64][9];

    float4 w[32];
    {
        const float4* src = (const float4*)(Whh1 + ((size_t)(g * HDIM + u0 + uur)) * HDIM) + c * 32;
#pragma unroll
        for (int k = 0; k < 32; k++) w[k] = src[k];
    }
    float creg = 0.0f;                       // cell state, thread-private (tid<128)
    const int bbc = tid >> 4, uuc = tid & 15;
    unsigned* myflags = flags + bg * 192;

    for (int t = 0; t < PLEN + HLEN; t++) {
        const int layer2 = (t >= PLEN) ? 1 : 0;
        const int tloc = layer2 ? t - PLEN : t;
        const int T = layer2 ? HLEN : PLEN;
        const float* xproj = layer2 ? xh : xp;
        float* outseq = layer2 ? outh : outp;
        float* hwr = (t & 1) ? hB : hA;
        const float* hrd = (t & 1) ? hA : hB;

        // prefetch gate pre-activations for THIS step (independent of h flag):
        // latency hides under the spin-wait + staging + GEMV.
        float gi = 0.f, gf = 0.f, gg = 0.f, go = 0.f;
        if (tid < 128) {
            size_t xb = ((size_t)(b0 + bbc) * T + tloc) * G4 + u0 + uuc;
            gi = xproj[xb];        gf = xproj[xb + 512];
            gg = xproj[xb + 1024]; go = xproj[xb + 1536];
        }

        if (t == PLEN) {   // reload layer-2 weights into VGPRs (uniform)
            const float4* src = (const float4*)(Whh2 + ((size_t)(g * HDIM + u0 + uur)) * HDIM) + c * 32;
#pragma unroll
            for (int k = 0; k < 32; k++) w[k] = src[k];
        }
        const bool have_h = (tloc != 0);
        if (have_h) {
            // wait: all 32 u-groups of this b-group stored h_{t-1}
            if (tid == 0) {
                while (__hip_atomic_load(&myflags[t - 1], __ATOMIC_RELAXED,
                                         __HIP_MEMORY_SCOPE_AGENT) != 32u)
                    __builtin_amdgcn_s_sleep(1);
            }
            __syncthreads();
            __asm__ volatile("" ::: "memory");
            // stage h_{t-1} (8 batches x 512) via LLC-coherent u64 loads, chunked
            const unsigned long long* hs64 =
                (const unsigned long long*)(hrd) + (size_t)b0 * 256;
#pragma unroll
            for (int i = 0; i < 8; i++) {
                int idx = tid + i * 256;
                int bb = idx >> 8, j = idx & 255;
                unsigned long long v = aload64(hs64 + bb * 256 + j);
                *(unsigned long long*)&hst[bb * CHROW + (j >> 6) * 132 + ((2 * j) & 127)] = v;
            }
            __syncthreads();
            // GEMV: gate row r, chunk c (weights in VGPRs, h broadcast from LDS)
#pragma unroll 1
            for (int bb = 0; bb < 8; bb++) {
                const float4* hv = (const float4*)&hst[bb * CHROW + c * 132];
                float ax = 0.f, ay = 0.f, az = 0.f, aw = 0.f;
#pragma unroll
                for (int k = 0; k < 32; k++) {
                    float4 a = w[k], x = hv[k];
                    ax += a.x * x.x; ay += a.y * x.y; az += a.z * x.z; aw += a.w * x.w;
                }
                float acc = (ax + ay) + (az + aw);
                acc += __shfl_xor(acc, 1);
                acc += __shfl_xor(acc, 2);
                if (c == 0) gsm[r][bb] = acc;
            }
        }
        __syncthreads();
        // cell update: thread (bb, uu), tid<128
        if (tid < 128) {
            const int b = b0 + bbc;
            if (have_h) {
                gi += gsm[uuc][bbc];
                gf += gsm[16 + uuc][bbc];
                gg += gsm[32 + uuc][bbc];
                go += gsm[48 + uuc][bbc];
            }
            float cn = sigf(gf) * creg + sigf(gi) * tanhfast(gg);
            float hn = sigf(go) * tanhfast(cn);
            creg = cn;
            outseq[((size_t)b * T + tloc) * HDIM + u0 + uuc] = hn;
            float pr = __shfl_xor(hn, 1);
            if ((uuc & 1) == 0) {
                float2 v2 = make_float2(hn, pr);
                astore64((unsigned long long*)(hwr + (size_t)b * HDIM + u0 + uuc),
                         *(unsigned long long*)&v2);
            }
        }
        __asm__ volatile("" ::: "memory");
        __builtin_amdgcn_s_waitcnt(0);   // h stores complete at LLC
        __syncthreads();
        if (tid == 0)
            __hip_atomic_fetch_add(&myflags[t], 1u, __ATOMIC_RELAXED,
                                   __HIP_MEMORY_SCOPE_AGENT);
    }
}

// ---------------------------------------------------------------------------
// a1t[b][p][h] = sum_j Wy[h][j] * outp[b][p][j]   (TRANSPOSED layout: [b][p][h])
__global__ __launch_bounds__(256) void a1_kernel(
    const float* __restrict__ Wy, const float* __restrict__ outp,
    float* __restrict__ a1t)
{
    __shared__ float os[16][260];
    __shared__ float wsh[16][260];
    int b = blockIdx.x, h0 = blockIdx.y * 16, p0 = blockIdx.z * 16;
    int tid = threadIdx.x, tx = tid & 15, ty = tid >> 4;
    float acc = 0.f;
    for (int kc = 0; kc < 2; kc++) {
        __syncthreads();
        for (int i = tid; i < 16 * 64; i += 256) {
            int row = i >> 6, k4 = i & 63;
            ((float4*)&os[row][0])[k4] =
                ((const float4*)(outp + (size_t)(b * PLEN + p0 + row) * HDIM + kc * 256))[k4];
            ((float4*)&wsh[row][0])[k4] =
                ((const float4*)(Wy + (size_t)(h0 + row) * HDIM + kc * 256))[k4];
        }
        __syncthreads();
        const float4* ov = (const float4*)&os[ty][0];    // p = p0+ty
        const float4* wv4 = (const float4*)&wsh[tx][0];  // h = h0+tx
#pragma unroll 8
        for (int k = 0; k < 64; k++) {
            float4 a = ov[k], w = wv4[k];
            acc += a.x * w.x + a.y * w.y + a.z * w.z + a.w * w.w;
        }
    }
    // coalesced in h (16 consecutive floats per p-row)
    a1t[((size_t)b * PLEN + p0 + ty) * HDIM + h0 + tx] = acc;
}

// ---------------------------------------------------------------------------
// persistent attention, flag-synced within batch-groups. 256 blocks x 256 thr.
// block = (ug, bg): 16 units (phases A/C), 4 premise positions (phase B), 8 batches.
// 48 weight rows (Wh/Wr/Wt x 16 units) in VGPRs of threads r<48.
// a1 slice (8b x 4p x 512h) lives in VGPRs (16 float4/thread), loaded ONCE.
// outp slice (8b x 128p x 16u) lives in LDS, loaded ONCE.
#define OSTR 2056   // 128*16 + 8 pad: phase-C gather lands 2-way max
__global__ __launch_bounds__(256, 1) void att_coop(
    const float* __restrict__ outh, const float* __restrict__ a1b,
    const float* __restrict__ outp,
    const float* __restrict__ Wh, const float* __restrict__ Wr,
    const float* __restrict__ Wt, const float* __restrict__ wv,
    float* __restrict__ a2buf, float* __restrict__ sbuf,
    float* __restrict__ rA, float* __restrict__ rB,
    unsigned* __restrict__ flags)
{
    const int tid = threadIdx.x;
    const int ug = blockIdx.x & 31;
    const int bg = blockIdx.x >> 5;
    const int u0 = ug * 16, b0 = bg * 8;
    const int r = tid >> 2, c = tid & 3;   // r<48: m = r>>4 (0:Wh 1:Wr 2:Wt), uu = r&15
    const int m = r >> 4, uur = r & 15;

    __shared__ __align__(16) float ops[8 * OSTR];    // persistent outp slice
    __shared__ __align__(16) float qa[8 * CHROW];    // chunked: q_t (A) / a2 (B)
    __shared__ __align__(16) float rst[8 * CHROW];   // chunked r staging
    __shared__ __align__(16) float scst[8][132];
    __shared__ float dsm[48][9];
    __shared__ float tts[16][9];
    __shared__ __align__(16) float wvs[512];

    float4 w[32];
    if (r < 48) {
        const float* W = (m == 0) ? Wh : ((m == 1) ? Wr : Wt);
        const float4* src = (const float4*)(W + (size_t)(u0 + uur) * HDIM) + c * 32;
#pragma unroll
        for (int k = 0; k < 32; k++) w[k] = src[k];
    }
    for (int i = tid; i < 128; i += 256)
        ((float4*)wvs)[i] = ((const float4*)wv)[i];

    // ---- one-time: outp slice -> LDS (64 KB, reused by all 64 steps)
    for (int i = tid; i < 8 * 128 * 4; i += 256) {
        int bb = i >> 9;
        int rem = i & 511;
        int p = rem >> 2, q = rem & 3;
        float4 v = *((const float4*)(outp + ((size_t)(b0 + bb) * PLEN + p) * HDIM + u0) + q);
        *((float4*)(ops + bb * OSTR + p * 16) + q) = v;
    }

    // ---- one-time: a1 slice -> VGPRs (16 float4/thread, coalesced)
    const int wvid = tid >> 6, lane = tid & 63;
    const int p0g = ug * 4;
    float4 a1r[8][2];
#pragma unroll
    for (int i = 0; i < 8; i++) {
        int pr = wvid * 8 + i;
        int bb = pr >> 2, pp = pr & 3;
        const float4* src = (const float4*)(a1b + ((size_t)(b0 + bb) * PLEN + p0g + pp) * HDIM) + lane;
        a1r[i][0] = src[0];
        a1r[i][1] = src[64];
    }

    unsigned* fA = flags + 1536 + bg * 64;
    unsigned* fB = flags + 1536 + 512 + bg * 64;
    unsigned* fC = flags + 1536 + 1024 + bg * 64;
    const int bbc = tid >> 4, uuc = tid & 15;

    for (int t = 0; t < HLEN; t++) {
        float* rwr = (t & 1) ? rB : rA;
        const float* rrd = (t & 1) ? rA : rB;

        // ---- phase A: a2 = q.Wh + r.Wr ; tt = tanh(r.Wt)
        // prefetch q_t (independent of fC flag): latency hides under spin-wait
        for (int i = tid; i < 8 * 128; i += 256) {
            int bb = i >> 7, k4 = i & 127;
            float4 v = ((const float4*)(outh + ((size_t)(b0 + bb) * HLEN + t) * HDIM))[k4];
            *(float4*)&qa[bb * CHROW + CH(4 * k4)] = v;
        }
        if (t > 0 && tid == 0) {
            while (__hip_atomic_load(&fC[t - 1], __ATOMIC_RELAXED,
                                     __HIP_MEMORY_SCOPE_AGENT) != 32u)
                __builtin_amdgcn_s_sleep(1);
        }
        __syncthreads();
        __asm__ volatile("" ::: "memory");
        if (t > 0) {
            const unsigned long long* rs64 =
                (const unsigned long long*)(rrd) + (size_t)b0 * 256;
#pragma unroll
            for (int i = 0; i < 8; i++) {
                int idx = tid + i * 256;
                int bb = idx >> 8, j = idx & 255;
                *(unsigned long long*)&rst[bb * CHROW + (j >> 6) * 132 + ((2 * j) & 127)] =
                    aload64(rs64 + bb * 256 + j);
            }
        }
        __syncthreads();
        if (r < 48 && (t > 0 || m == 0)) {
#pragma unroll 1
            for (int bb = 0; bb < 8; bb++) {
                const float4* sv = (const float4*)((m == 0) ? &qa[bb * CHROW + c * 132]
                                                            : &rst[bb * CHROW + c * 132]);
                float ax = 0.f, ay = 0.f, az = 0.f, aw = 0.f;
#pragma unroll
                for (int k = 0; k < 32; k++) {
                    float4 a = w[k], x = sv[k];
                    ax += a.x * x.x; ay += a.y * x.y; az += a.z * x.z; aw += a.w * x.w;
                }
                float acc = (ax + ay) + (az + aw);
                acc += __shfl_xor(acc, 1);
                acc += __shfl_xor(acc, 2);
                if (c == 0) dsm[r][bb] = acc;
            }
        }
        __syncthreads();
        if (tid < 128) {
            float aq = dsm[uuc][bbc];
            float ar = (t > 0) ? dsm[16 + uuc][bbc] : 0.0f;
            float at = (t > 0) ? dsm[32 + uuc][bbc] : 0.0f;
            float a2v = aq + ar;
            tts[uuc][bbc] = (t > 0) ? tanhfast(at) : 0.0f;
            float pr = __shfl_xor(a2v, 1);
            if ((uuc & 1) == 0) {
                float2 v2 = make_float2(a2v, pr);
                astore64((unsigned long long*)(a2buf + (size_t)(b0 + bbc) * HDIM + u0 + uuc),
                         *(unsigned long long*)&v2);
            }
        }
        __asm__ volatile("" ::: "memory");
        __builtin_amdgcn_s_waitcnt(0);
        __syncthreads();
        if (tid == 0)
            __hip_atomic_fetch_add(&fA[t], 1u, __ATOMIC_RELAXED, __HIP_MEMORY_SCOPE_AGENT);

        // ---- phase B: s[b][p-slice] = sum_h wv[h]*tanh(a1 + a2)
        // a1 is in VGPRs; a2 staged into qa (aliases dead q_t), chunked layout.
        if (tid == 0) {
            while (__hip_atomic_load(&fA[t], __ATOMIC_RELAXED,
                                     __HIP_MEMORY_SCOPE_AGENT) != 32u)
                __builtin_amdgcn_s_sleep(1);
        }
        __syncthreads();
        __asm__ volatile("" ::: "memory");
        {
            const unsigned long long* a64 =
                (const unsigned long long*)(a2buf) + (size_t)b0 * 256;
#pragma unroll
            for (int i = 0; i < 8; i++) {
                int idx = tid + i * 256;
                int bb = idx >> 8, j = idx & 255;
                *(unsigned long long*)&qa[bb * CHROW + (j >> 6) * 132 + ((2 * j) & 127)] =
                    aload64(a64 + bb * 256 + j);
            }
        }
        __syncthreads();
        {
#pragma unroll 2
            for (int i = 0; i < 8; i++) {
                int pr = wvid * 8 + i;
                int bb = pr >> 2, pp = pr & 3;
                float s = 0.f;
#pragma unroll
                for (int k = 0; k < 2; k++) {
                    int h4 = lane + 64 * k;
                    float4 av = a1r[i][k];
                    float4 a2v = *(const float4*)&qa[bb * CHROW + CH(4 * h4)];
                    float4 wv4 = ((const float4*)wvs)[h4];
                    s += wv4.x * tanhfast(av.x + a2v.x)
                       + wv4.y * tanhfast(av.y + a2v.y)
                       + wv4.z * tanhfast(av.z + a2v.z)
                       + wv4.w * tanhfast(av.w + a2v.w);
                }
#pragma unroll
                for (int o = 1; o < 64; o <<= 1) s += __shfl_xor(s, o);
                if (lane == 0)
                    astore32(sbuf + (size_t)(b0 + bb) * PLEN + p0g + pp, s);
            }
        }
        __asm__ volatile("" ::: "memory");
        __builtin_amdgcn_s_waitcnt(0);
        __syncthreads();
        if (tid == 0)
            __hip_atomic_fetch_add(&fB[t], 1u, __ATOMIC_RELAXED, __HIP_MEMORY_SCOPE_AGENT);

        // ---- phase C: softmax over p (redundant per block) + r update from LDS-resident outp
        if (tid == 0) {
            while (__hip_atomic_load(&fB[t], __ATOMIC_RELAXED,
                                     __HIP_MEMORY_SCOPE_AGENT) != 32u)
                __builtin_amdgcn_s_sleep(1);
        }
        __syncthreads();
        __asm__ volatile("" ::: "memory");
        {
            const unsigned long long* s64 =
                (const unsigned long long*)(sbuf) + (size_t)b0 * 64;
#pragma unroll
            for (int i = 0; i < 2; i++) {
                int idx = tid + i * 256;
                int bb = idx >> 6, j = idx & 63;
                *(unsigned long long*)&scst[bb][j * 2] = aload64(s64 + bb * 64 + j);
            }
        }
        __syncthreads();
        {
            const int bb = tid >> 5, j = tid & 31;
            float4 v = *(float4*)&scst[bb][j * 4];
            float mx = fmaxf(fmaxf(v.x, v.y), fmaxf(v.z, v.w));
#pragma unroll
            for (int o = 1; o < 32; o <<= 1) mx = fmaxf(mx, __shfl_xor(mx, o));
            float ex = __expf(v.x - mx), ey = __expf(v.y - mx);
            float ez = __expf(v.z - mx), ew = __expf(v.w - mx);
            float ssum = (ex + ey) + (ez + ew);
#pragma unroll
            for (int o = 1; o < 32; o <<= 1) ssum += __shfl_xor(ssum, o);
            float inv = 1.0f / ssum;
            float4 sc4 = make_float4(ex * inv, ey * inv, ez * inv, ew * inv);
            *(float4*)&scst[bb][j * 4] = sc4;
        }
        __syncthreads();
        if (tid < 128) {
            float acc = tts[uuc][bbc];
            const float* opb = ops + bbc * OSTR + uuc;
#pragma unroll 8
            for (int p = 0; p < PLEN; p++)
                acc += scst[bbc][p] * opb[p * 16];
            float pr = __shfl_xor(acc, 1);
            if ((uuc & 1) == 0) {
                float2 v2 = make_float2(acc, pr);
                astore64((unsigned long long*)(rwr + (size_t)(b0 + bbc) * HDIM + u0 + uuc),
                         *(unsigned long long*)&v2);
            }
        }
        __asm__ volatile("" ::: "memory");
        __builtin_amdgcn_s_waitcnt(0);
        __syncthreads();
        if (tid == 0)
            __hip_atomic_fetch_add(&fC[t], 1u, __ATOMIC_RELAXED, __HIP_MEMORY_SCOPE_AGENT);
    }
}

// ---------------------------------------------------------------------------
// final: rep = tanh(r.fc1^T + b1 + hn.fc2^T + b2); out = rep.fc3^T + b3
__global__ __launch_bounds__(256) void final_kernel(
    const float* __restrict__ r, const float* __restrict__ outh,
    const float* __restrict__ fc1w, const float* __restrict__ fc1b,
    const float* __restrict__ fc2w, const float* __restrict__ fc2b,
    const float* __restrict__ fc3w, const float* __restrict__ fc3b,
    float* __restrict__ out)
{
    int b = blockIdx.x, tid = threadIdx.x;
    __shared__ float rs[HDIM], hs[HDIM], rep[HDIM], red[256];
    for (int i = tid; i < 128; i += 256) {
        ((float4*)rs)[i] = ((const float4*)(r + (size_t)b * HDIM))[i];
        ((float4*)hs)[i] = ((const float4*)(outh + ((size_t)(b * HLEN + HLEN - 1)) * HDIM))[i];
    }
    __syncthreads();
    for (int u = tid; u < HDIM; u += 256) {
        const float4* w1 = (const float4*)(fc1w + (size_t)u * HDIM);
        const float4* w2 = (const float4*)(fc2w + (size_t)u * HDIM);
        float a = 0.f, bacc = 0.f;
        for (int k = 0; k < 128; k++) {
            float4 rv = ((float4*)rs)[k], hv = ((float4*)hs)[k];
            float4 x = w1[k]; a    += rv.x * x.x + rv.y * x.y + rv.z * x.z + rv.w * x.w;
            float4 y = w2[k]; bacc += hv.x * y.x + hv.y * y.y + hv.z * y.z + hv.w * y.w;
        }
        rep[u] = tanhfast(a + fc1b[u] + bacc + fc2b[u]);
    }
    __syncthreads();
    for (int cix = 0; cix < NCLS; cix++) {
        red[tid] = rep[tid] * fc3w[(size_t)cix * HDIM + tid]
                 + rep[tid + 256] * fc3w[(size_t)cix * HDIM + tid + 256];
        __syncthreads();
        for (int off = 128; off; off >>= 1) {
            if (tid < off) red[tid] += red[tid + off];
            __syncthreads();
        }
        if (tid == 0) out[b * NCLS + cix] = red[0] + fc3b[cix];
        __syncthreads();
    }
}

// ---------------------------------------------------------------------------
extern "C" void kernel_launch(void* const* d_in, const int* in_sizes, int n_in,
                              void* d_out, int out_size, void* d_ws, size_t ws_size,
                              hipStream_t stream)
{
    const int*   premise = (const int*)d_in[0];
    const int*   hyp     = (const int*)d_in[1];
    const float* emb     = (const float*)d_in[2];
    const float* Wih1    = (const float*)d_in[3];
    const float* Whh1    = (const float*)d_in[4];
    const float* bih1    = (const float*)d_in[5];
    const float* bhh1    = (const float*)d_in[6];
    const float* Wih2    = (const float*)d_in[7];
    const float* Whh2    = (const float*)d_in[8];
    const float* bih2    = (const float*)d_in[9];
    const float* bhh2    = (const float*)d_in[10];
    const float* Wy      = (const float*)d_in[11];
    const float* Wh      = (const float*)d_in[12];
    const float* Wr      = (const float*)d_in[13];
    const float* Wt      = (const float*)d_in[14];
    const float* wv      = (const float*)d_in[15];
    const float* fc1w    = (const float*)d_in[16];
    const float* fc1b    = (const float*)d_in[17];
    const float* fc2w    = (const float*)d_in[18];
    const float* fc2b    = (const float*)d_in[19];
    const float* fc3w    = (const float*)d_in[20];
    const float* fc3b    = (const float*)d_in[21];
    float* out = (float*)d_out;

    float* ws = (float*)d_ws;
    size_t off = 0;
    float* xp    = ws + off; off += (size_t)BSZ * PLEN * G4;
    float* xh    = ws + off; off += (size_t)BSZ * HLEN * G4;
    float* outp  = ws + off; off += (size_t)BSZ * PLEN * HDIM;
    float* outhp = ws + off; off += (size_t)BSZ * HLEN * HDIM;
    float* a1b   = ws + off; off += (size_t)BSZ * HDIM * PLEN;   // stored as [b][p][h]
    float* hAb   = ws + off; off += BSZ * HDIM;
    float* hBb   = ws + off; off += BSZ * HDIM;
    float* a2buf = ws + off; off += BSZ * HDIM;
    float* rAb   = ws + off; off += BSZ * HDIM;
    float* rBb   = ws + off; off += BSZ * HDIM;
    float* sbuf  = ws + off; off += BSZ * PLEN;
    unsigned* flags = (unsigned*)(ws + off); off += 4096;
    if (ws_size < off * sizeof(float)) return;

    // zero flag counters every call (d_ws is re-poisoned before each launch)
    flag_init<<<dim3(16), dim3(256), 0, stream>>>(flags);

    // input projections (biases folded in)
    proj_kernel<<<dim3(BSZ * PLEN / 16, G4 / 32), dim3(256), 0, stream>>>(
        premise, emb, Wih1, bih1, bhh1, xp);
    proj_kernel<<<dim3(BSZ * HLEN / 16, G4 / 32), dim3(256), 0, stream>>>(
        hyp, emb, Wih2, bih2, bhh2, xh);

    // both LSTMs, persistent, per-b-group flag sync (no L2-flushing fences)
    lstm_coop<<<dim3(256), dim3(256), 0, stream>>>(
        xp, xh, Whh1, Whh2, outp, outhp, hAb, hBb, flags);

    // a1t = einsum('hj,bpj->bph', Wy, outp)   (transposed: [b][p][h])
    a1_kernel<<<dim3(BSZ, HDIM / 16, PLEN / 16), dim3(256), 0, stream>>>(Wy, outp, a1b);

    // attention recurrence, persistent, per-b-group flag sync
    att_coop<<<dim3(256), dim3(256), 0, stream>>>(
        outhp, a1b, outp, Wh, Wr, Wt, wv, a2buf, sbuf, rAb, rBb, flags);

    // final classifier: r after step 63 lives in rB (63 & 1 == 1)
    final_kernel<<<dim3(BSZ), dim3(256), 0, stream>>>(
        rBb, outhp, fc1w, fc1b, fc2w, fc2b, fc3w, fc3b, out);
}

// Round 4
// 3664.162 us; speedup vs baseline: 1.6796x; 1.2297x over previous
//
#include <hip/hip_runtime.h>
#include <math.h>

#define BSZ 64
#define PLEN 128
#define HLEN 64
#define EDIM 300
#define HDIM 512
#define G4 2048   // 4*HDIM
#define NCLS 3

// att tag offset: lstm layer-2 reuses rA/rB for its h exchange (tags 129..192);
// att tags start at 1000+ so stale lstm tags can never falsely match.
#define TOFF 1000u
// spin guard: protocol-correct runs never hit it; a bug degrades to a
// wrong answer (reportable) instead of a hung container.
#define SPIN_CAP (1 << 18)

// chunked 512-float vector layout: 4 chunks of 132 floats (128 data + 4 pad).
// float f (0..511) lives at CH(f) = (f>>7)*132 + (f&127).
// GEMV chunk read c*132+4k -> banks 4c+4k: conflict-free broadcast.
#define CHROW 528
#define CH(f) ((((f) >> 7) * 132) + ((f) & 127))

__device__ __forceinline__ float sigf(float x) { return 1.0f / (1.0f + __expf(-x)); }
__device__ __forceinline__ float tanhfast(float x) { return 1.0f - 2.0f / (__expf(2.0f * x) + 1.0f); }

// relaxed agent-scope atomic helpers: LLC-coherent, no L2 flush/invalidate
__device__ __forceinline__ unsigned long long aload64(const unsigned long long* p) {
    return __hip_atomic_load(p, __ATOMIC_RELAXED, __HIP_MEMORY_SCOPE_AGENT);
}
__device__ __forceinline__ void astore64(unsigned long long* p, unsigned long long v) {
    __hip_atomic_store(p, v, __ATOMIC_RELAXED, __HIP_MEMORY_SCOPE_AGENT);
}
// tagged-value pack: high 32 = step tag, low 32 = float bits. Data-flow sync:
// consumer spins on the DATA word until tag matches -> ONE LLC round trip,
// no flags, no atomics, no producer-side store-ack wait.
__device__ __forceinline__ unsigned long long tpack(float v, unsigned tag) {
    return ((unsigned long long)tag << 32) | (unsigned long long)__float_as_uint(v);
}
__device__ __forceinline__ float tval(unsigned long long v) { return __uint_as_float((unsigned)v); }
__device__ __forceinline__ unsigned ttag(unsigned long long v) { return (unsigned)(v >> 32); }

// zero the tagged-exchange buffers (d_ws is poisoned before each launch;
// expected tags are >=1, so zeroed tags never falsely match)
__global__ __launch_bounds__(256) void ws_zero(unsigned long long* p) {
    p[(size_t)blockIdx.x * 256 + threadIdx.x] = 0ull;
}

// ---------------------------------------------------------------------------
// input projection GEMM: out[m][row] = emb[toks[m]] . Wih[row] + bih[row]+bhh[row]
// 32x64 tile, 8 outputs/thread (2m x 4n), K chunked by 100 (LDS stride 100:
// 100%32=4 -> w-reads land on distinct bank quads).
__global__ __launch_bounds__(256) void proj_kernel(
    const int* __restrict__ toks, const float* __restrict__ emb,
    const float* __restrict__ Wih, const float* __restrict__ bih,
    const float* __restrict__ bhh, float* __restrict__ out)
{
    __shared__ float es[32 * 100];
    __shared__ float wsh[64 * 100];
    __shared__ int tks[32];
    const int m0 = blockIdx.x * 32, r0 = blockIdx.y * 64;
    const int tid = threadIdx.x;
    const int tx = tid & 15, ty = tid >> 4;
    float acc[2][4] = {{0.f, 0.f, 0.f, 0.f}, {0.f, 0.f, 0.f, 0.f}};
    if (tid < 32) tks[tid] = toks[m0 + tid];
    __syncthreads();
    for (int kc = 0; kc < 3; kc++) {
        if (kc) __syncthreads();
        for (int i = tid; i < 800; i += 256) {
            int row = i / 25, k4 = i % 25;
            ((float4*)es)[i] = ((const float4*)(emb + (size_t)tks[row] * EDIM + kc * 100))[k4];
        }
        for (int i = tid; i < 1600; i += 256) {
            int row = i / 25, k4 = i % 25;
            ((float4*)wsh)[i] = ((const float4*)(Wih + (size_t)(r0 + row) * EDIM + kc * 100))[k4];
        }
        __syncthreads();
        const float4* e0 = (const float4*)es + ty * 25;
        const float4* e1 = e0 + 16 * 25;
        const float4* w0 = (const float4*)wsh + tx * 25;
#pragma unroll
        for (int k = 0; k < 25; k++) {
            float4 ea = e0[k], eb = e1[k];
#pragma unroll
            for (int j = 0; j < 4; j++) {
                float4 w = w0[k + j * 400];
                acc[0][j] += ea.x * w.x + ea.y * w.y + ea.z * w.z + ea.w * w.w;
                acc[1][j] += eb.x * w.x + eb.y * w.y + eb.z * w.z + eb.w * w.w;
            }
        }
    }
#pragma unroll
    for (int j = 0; j < 4; j++) {
        int rr = r0 + tx + j * 16;
        float bsum = bih[rr] + bhh[rr];
        out[(size_t)(m0 + ty) * G4 + rr]      = acc[0][j] + bsum;
        out[(size_t)(m0 + ty + 16) * G4 + rr] = acc[1][j] + bsum;
    }
}

// ---------------------------------------------------------------------------
// persistent LSTM, tagged-data synced within batch-groups. 256 blocks x 256 thr.
// block = (ug 0..31, bg 0..7): units u0..u0+15, batches b0..b0+7.
// h exchange: u64 (tag | h_bits) per (b,u); consumer spins until tag == t.
// LAYER BOUNDARY FIX: layer 2 uses its own buffer pair (hC/hD). At t=PLEN the
// spin is skipped (tloc==0), so writing into layer-1's hA would overwrite
// tag-127 data that laggard blocks are still spinning on -> deadlock.
__global__ __launch_bounds__(256, 1) void lstm_coop(
    const float* __restrict__ xp, const float* __restrict__ xh,
    const float* __restrict__ Whh1, const float* __restrict__ Whh2,
    float* __restrict__ outp, float* __restrict__ outh,
    unsigned long long* __restrict__ hA, unsigned long long* __restrict__ hB,
    unsigned long long* __restrict__ hC, unsigned long long* __restrict__ hD)
{
    const int tid = threadIdx.x;
    const int ug = blockIdx.x & 31;
    const int bg = blockIdx.x >> 5;
    const int u0 = ug * 16, b0 = bg * 8;
    const int r = tid >> 2, c = tid & 3;   // r 0..63 = g*16+uu
    const int g = r >> 4, uur = r & 15;

    __shared__ __align__(16) float hst[8 * CHROW];   // chunked h staging
    __shared__ float gsm[64][9];

    float4 w[32];
    {
        const float4* src = (const float4*)(Whh1 + ((size_t)(g * HDIM + u0 + uur)) * HDIM) + c * 32;
#pragma unroll
        for (int k = 0; k < 32; k++) w[k] = src[k];
    }
    float creg = 0.0f;                       // cell state, thread-private (tid<128)
    const int bbc = tid >> 4, uuc = tid & 15;

    for (int t = 0; t < PLEN + HLEN; t++) {
        const int layer2 = (t >= PLEN) ? 1 : 0;
        const int tloc = layer2 ? t - PLEN : t;
        const int T = layer2 ? HLEN : PLEN;
        const float* xproj = layer2 ? xh : xp;
        float* outseq = layer2 ? outh : outp;
        unsigned long long* wA = layer2 ? hC : hA;
        unsigned long long* wB = layer2 ? hD : hB;
        unsigned long long* hwr = (t & 1) ? wB : wA;
        const unsigned long long* hrd = (t & 1) ? wA : wB;

        // prefetch gate pre-activations for THIS step (latency hides under
        // the tag-spin + staging + GEMV)
        float gi = 0.f, gf = 0.f, gg = 0.f, go = 0.f;
        if (tid < 128) {
            size_t xb = ((size_t)(b0 + bbc) * T + tloc) * G4 + u0 + uuc;
            gi = xproj[xb];        gf = xproj[xb + 512];
            gg = xproj[xb + 1024]; go = xproj[xb + 1536];
        }

        if (t == PLEN) {   // reload layer-2 weights into VGPRs (uniform)
            const float4* src = (const float4*)(Whh2 + ((size_t)(g * HDIM + u0 + uur)) * HDIM) + c * 32;
#pragma unroll
            for (int k = 0; k < 32; k++) w[k] = src[k];
        }
        const bool have_h = (tloc != 0);
        if (have_h) {
            // tagged staging: 16 u64/thread covering 8 batches x 512 units
            const unsigned long long* src = hrd + (size_t)b0 * 512;
            unsigned long long v[16];
            const unsigned expt = (unsigned)t;
            int guard = 0;
            while (true) {
                bool ok = true;
#pragma unroll
                for (int i = 0; i < 16; i++) v[i] = aload64(src + tid + i * 256);
#pragma unroll
                for (int i = 0; i < 16; i++) ok &= (ttag(v[i]) == expt);
                if (__all(ok)) break;
                if (++guard > SPIN_CAP) break;
                __builtin_amdgcn_s_sleep(1);
            }
            __asm__ volatile("" ::: "memory");
#pragma unroll
            for (int i = 0; i < 16; i++) {
                int idx = tid + i * 256;
                int bb = idx >> 9, u = idx & 511;
                hst[bb * CHROW + CH(u)] = tval(v[i]);
            }
            __syncthreads();
            // GEMV: gate row r, chunk c (weights in VGPRs, h broadcast from LDS)
#pragma unroll 1
            for (int bb = 0; bb < 8; bb++) {
                const float4* hv = (const float4*)&hst[bb * CHROW + c * 132];
                float ax = 0.f, ay = 0.f, az = 0.f, aw = 0.f;
#pragma unroll
                for (int k = 0; k < 32; k++) {
                    float4 a = w[k], x = hv[k];
                    ax += a.x * x.x; ay += a.y * x.y; az += a.z * x.z; aw += a.w * x.w;
                }
                float acc = (ax + ay) + (az + aw);
                acc += __shfl_xor(acc, 1);
                acc += __shfl_xor(acc, 2);
                if (c == 0) gsm[r][bb] = acc;
            }
        }
        __syncthreads();   // gsm ready; also protects hst vs next staging
        // cell update: thread (bb, uu), tid<128
        if (tid < 128) {
            const int b = b0 + bbc;
            if (have_h) {
                gi += gsm[uuc][bbc];
                gf += gsm[16 + uuc][bbc];
                gg += gsm[32 + uuc][bbc];
                go += gsm[48 + uuc][bbc];
            }
            float cn = sigf(gf) * creg + sigf(gi) * tanhfast(gg);
            float hn = sigf(go) * tanhfast(cn);
            creg = cn;
            // tagged h store FIRST (consumer-visible sync), then plain outseq
            astore64(hwr + (size_t)b * 512 + u0 + uuc, tpack(hn, (unsigned)(t + 1)));
            outseq[((size_t)b * T + tloc) * HDIM + u0 + uuc] = hn;
        }
        // no waitcnt, no flag, no extra barrier: tags gate everything
    }
}

// ---------------------------------------------------------------------------
// a1t[b][p][h] = sum_j Wy[h][j] * outp[b][p][j]   (layout [b][p][h])
// 32x64 tile, 8 outputs/thread, K chunked by 128 (LDS f4-stride 33).
__global__ __launch_bounds__(256) void a1_kernel(
    const float* __restrict__ Wy, const float* __restrict__ outp,
    float* __restrict__ a1t)
{
    __shared__ float os[32 * 132];
    __shared__ float wsh[64 * 132];
    const int b = blockIdx.x, p0 = blockIdx.y * 32, h0 = blockIdx.z * 64;
    const int tid = threadIdx.x;
    const int tx = tid & 15, ty = tid >> 4;
    float acc[2][4] = {{0.f, 0.f, 0.f, 0.f}, {0.f, 0.f, 0.f, 0.f}};
    for (int kc = 0; kc < 4; kc++) {
        if (kc) __syncthreads();
        for (int i = tid; i < 1024; i += 256) {
            int row = i >> 5, k4 = i & 31;
            ((float4*)os)[row * 33 + k4] =
                ((const float4*)(outp + ((size_t)(b * PLEN) + p0 + row) * HDIM + kc * 128))[k4];
        }
        for (int i = tid; i < 2048; i += 256) {
            int row = i >> 5, k4 = i & 31;
            ((float4*)wsh)[row * 33 + k4] =
                ((const float4*)(Wy + (size_t)(h0 + row) * HDIM + kc * 128))[k4];
        }
        __syncthreads();
        const float4* o0 = (const float4*)os + ty * 33;
        const float4* o1 = o0 + 16 * 33;
        const float4* w0 = (const float4*)wsh + tx * 33;
#pragma unroll
        for (int k = 0; k < 32; k++) {
            float4 ea = o0[k], eb = o1[k];
#pragma unroll
            for (int j = 0; j < 4; j++) {
                float4 w = w0[k + j * 528];
                acc[0][j] += ea.x * w.x + ea.y * w.y + ea.z * w.z + ea.w * w.w;
                acc[1][j] += eb.x * w.x + eb.y * w.y + eb.z * w.z + eb.w * w.w;
            }
        }
    }
#pragma unroll
    for (int j = 0; j < 4; j++) {
        int hh = h0 + tx + j * 16;
        a1t[((size_t)b * PLEN + p0 + ty) * HDIM + hh]      = acc[0][j];
        a1t[((size_t)b * PLEN + p0 + ty + 16) * HDIM + hh] = acc[1][j];
    }
}

// ---------------------------------------------------------------------------
// persistent attention, tagged-data synced. 256 blocks x 256 thr.
// phase tags (TOFF-offset): A stores a2 with TOFF+3t+1; B stores s with
// TOFF+3t+2; C stores r with TOFF+3t+3. rA/rB hold stale lstm layer-2 tags
// (129..192) at entry; TOFF+3t (>=1003) never collides.
#define OSTR 2056   // 128*16 + 8 pad
__global__ __launch_bounds__(256, 1) void att_coop(
    const float* __restrict__ outh, const float* __restrict__ a1b,
    const float* __restrict__ outp,
    const float* __restrict__ Wh, const float* __restrict__ Wr,
    const float* __restrict__ Wt, const float* __restrict__ wv,
    unsigned long long* __restrict__ a2buf, unsigned long long* __restrict__ sbuf,
    unsigned long long* __restrict__ rA, unsigned long long* __restrict__ rB)
{
    const int tid = threadIdx.x;
    const int ug = blockIdx.x & 31;
    const int bg = blockIdx.x >> 5;
    const int u0 = ug * 16, b0 = bg * 8;
    const int r = tid >> 2, c = tid & 3;   // r<48: m = r>>4 (0:Wh 1:Wr 2:Wt), uu = r&15
    const int m = r >> 4, uur = r & 15;

    __shared__ __align__(16) float ops[8 * OSTR];    // persistent outp slice
    __shared__ __align__(16) float qa[8 * CHROW];    // chunked: q_t (A) / a2 (B)
    __shared__ __align__(16) float rst[8 * CHROW];   // chunked r staging
    __shared__ __align__(16) float scst[8][132];
    __shared__ float dsm[48][9];
    __shared__ float tts[16][9];
    __shared__ __align__(16) float wvs[512];

    float4 w[32];
    if (r < 48) {
        const float* W = (m == 0) ? Wh : ((m == 1) ? Wr : Wt);
        const float4* src = (const float4*)(W + (size_t)(u0 + uur) * HDIM) + c * 32;
#pragma unroll
        for (int k = 0; k < 32; k++) w[k] = src[k];
    }
    for (int i = tid; i < 128; i += 256)
        ((float4*)wvs)[i] = ((const float4*)wv)[i];

    // one-time: outp slice -> LDS (reused by all 64 steps)
    for (int i = tid; i < 8 * 128 * 4; i += 256) {
        int bb = i >> 9;
        int rem = i & 511;
        int p = rem >> 2, q = rem & 3;
        float4 v = *((const float4*)(outp + ((size_t)(b0 + bb) * PLEN + p) * HDIM + u0) + q);
        *((float4*)(ops + bb * OSTR + p * 16) + q) = v;
    }

    // one-time: a1 slice -> VGPRs (16 float4/thread, coalesced)
    const int wvid = tid >> 6, lane = tid & 63;
    const int p0g = ug * 4;
    float4 a1r[8][2];
#pragma unroll
    for (int i = 0; i < 8; i++) {
        int pr = wvid * 8 + i;
        int bb = pr >> 2, pp = pr & 3;
        const float4* src = (const float4*)(a1b + ((size_t)(b0 + bb) * PLEN + p0g + pp) * HDIM) + lane;
        a1r[i][0] = src[0];
        a1r[i][1] = src[64];
    }

    const int bbc = tid >> 4, uuc = tid & 15;

    for (int t = 0; t < HLEN; t++) {
        unsigned long long* rwr = (t & 1) ? rB : rA;
        const unsigned long long* rrd = (t & 1) ? rA : rB;

        // ---- phase A: a2 = q.Wh + r.Wr ; tt = tanh(r.Wt)
        // stage q_t (plain loads; prior-kernel data) into qa chunked
        for (int i = tid; i < 8 * 128; i += 256) {
            int bb = i >> 7, k4 = i & 127;
            float4 v = ((const float4*)(outh + ((size_t)(b0 + bb) * HLEN + t) * HDIM))[k4];
            *(float4*)&qa[bb * CHROW + CH(4 * k4)] = v;
        }
        if (t > 0) {
            // tagged stage of r (expect tag TOFF + 3(t-1)+3 = TOFF+3t)
            const unsigned long long* src = rrd + (size_t)b0 * 512;
            unsigned long long v[16];
            const unsigned expt = TOFF + (unsigned)(3 * t);
            int guard = 0;
            while (true) {
                bool ok = true;
#pragma unroll
                for (int i = 0; i < 16; i++) v[i] = aload64(src + tid + i * 256);
#pragma unroll
                for (int i = 0; i < 16; i++) ok &= (ttag(v[i]) == expt);
                if (__all(ok)) break;
                if (++guard > SPIN_CAP) break;
                __builtin_amdgcn_s_sleep(1);
            }
            __asm__ volatile("" ::: "memory");
#pragma unroll
            for (int i = 0; i < 16; i++) {
                int idx = tid + i * 256;
                int bb = idx >> 9, u = idx & 511;
                rst[bb * CHROW + CH(u)] = tval(v[i]);
            }
        }
        __syncthreads();
        if (r < 48 && (t > 0 || m == 0)) {
#pragma unroll 1
            for (int bb = 0; bb < 8; bb++) {
                const float4* sv = (const float4*)((m == 0) ? &qa[bb * CHROW + c * 132]
                                                            : &rst[bb * CHROW + c * 132]);
                float ax = 0.f, ay = 0.f, az = 0.f, aw = 0.f;
#pragma unroll
                for (int k = 0; k < 32; k++) {
                    float4 a = w[k], x = sv[k];
                    ax += a.x * x.x; ay += a.y * x.y; az += a.z * x.z; aw += a.w * x.w;
                }
                float acc = (ax + ay) + (az + aw);
                acc += __shfl_xor(acc, 1);
                acc += __shfl_xor(acc, 2);
                if (c == 0) dsm[r][bb] = acc;
            }
        }
        __syncthreads();
        if (tid < 128) {
            float aq = dsm[uuc][bbc];
            float ar = (t > 0) ? dsm[16 + uuc][bbc] : 0.0f;
            float at = (t > 0) ? dsm[32 + uuc][bbc] : 0.0f;
            float a2v = aq + ar;
            tts[uuc][bbc] = (t > 0) ? tanhfast(at) : 0.0f;
            astore64(a2buf + (size_t)(b0 + bbc) * 512 + u0 + uuc,
                     tpack(a2v, TOFF + (unsigned)(3 * t + 1)));
        }

        // ---- phase B: s[b][p-slice] = sum_h wv[h]*tanh(a1 + a2)
        {
            // tagged stage of a2 into qa (aliases dead q_t); expect TOFF+3t+1
            const unsigned long long* src = a2buf + (size_t)b0 * 512;
            unsigned long long v[16];
            const unsigned expt = TOFF + (unsigned)(3 * t + 1);
            int guard = 0;
            while (true) {
                bool ok = true;
#pragma unroll
                for (int i = 0; i < 16; i++) v[i] = aload64(src + tid + i * 256);
#pragma unroll
                for (int i = 0; i < 16; i++) ok &= (ttag(v[i]) == expt);
                if (__all(ok)) break;
                if (++guard > SPIN_CAP) break;
                __builtin_amdgcn_s_sleep(1);
            }
            __asm__ volatile("" ::: "memory");
#pragma unroll
            for (int i = 0; i < 16; i++) {
                int idx = tid + i * 256;
                int bb = idx >> 9, u = idx & 511;
                qa[bb * CHROW + CH(u)] = tval(v[i]);
            }
        }
        __syncthreads();
        {
#pragma unroll 2
            for (int i = 0; i < 8; i++) {
                int pr = wvid * 8 + i;
                int bb = pr >> 2, pp = pr & 3;
                float s = 0.f;
#pragma unroll
                for (int k = 0; k < 2; k++) {
                    int h4 = lane + 64 * k;
                    float4 av = a1r[i][k];
                    float4 a2v = *(const float4*)&qa[bb * CHROW + CH(4 * h4)];
                    float4 wv4 = ((const float4*)wvs)[h4];
                    s += wv4.x * tanhfast(av.x + a2v.x)
                       + wv4.y * tanhfast(av.y + a2v.y)
                       + wv4.z * tanhfast(av.z + a2v.z)
                       + wv4.w * tanhfast(av.w + a2v.w);
                }
#pragma unroll
                for (int o = 1; o < 64; o <<= 1) s += __shfl_xor(s, o);
                if (lane == 0)
                    astore64(sbuf + (size_t)(b0 + bb) * PLEN + p0g + pp,
                             tpack(s, TOFF + (unsigned)(3 * t + 2)));
            }
        }

        // ---- phase C: softmax over p (redundant per block) + r update
        {
            // tagged stage of s; expect TOFF+3t+2
            const unsigned long long* src = sbuf + (size_t)b0 * 128;
            unsigned long long v[4];
            const unsigned expt = TOFF + (unsigned)(3 * t + 2);
            int guard = 0;
            while (true) {
                bool ok = true;
#pragma unroll
                for (int i = 0; i < 4; i++) v[i] = aload64(src + tid + i * 256);
#pragma unroll
                for (int i = 0; i < 4; i++) ok &= (ttag(v[i]) == expt);
                if (__all(ok)) break;
                if (++guard > SPIN_CAP) break;
                __builtin_amdgcn_s_sleep(1);
            }
            __asm__ volatile("" ::: "memory");
#pragma unroll
            for (int i = 0; i < 4; i++) {
                int idx = tid + i * 256;
                int bb = idx >> 7, j = idx & 127;
                scst[bb][j] = tval(v[i]);
            }
        }
        __syncthreads();
        {
            const int bb = tid >> 5, j = tid & 31;
            float4 v = *(float4*)&scst[bb][j * 4];
            float mx = fmaxf(fmaxf(v.x, v.y), fmaxf(v.z, v.w));
#pragma unroll
            for (int o = 1; o < 32; o <<= 1) mx = fmaxf(mx, __shfl_xor(mx, o));
            float ex = __expf(v.x - mx), ey = __expf(v.y - mx);
            float ez = __expf(v.z - mx), ew = __expf(v.w - mx);
            float ssum = (ex + ey) + (ez + ew);
#pragma unroll
            for (int o = 1; o < 32; o <<= 1) ssum += __shfl_xor(ssum, o);
            float inv = 1.0f / ssum;
            float4 sc4 = make_float4(ex * inv, ey * inv, ez * inv, ew * inv);
            *(float4*)&scst[bb][j * 4] = sc4;
        }
        __syncthreads();
        if (tid < 128) {
            float acc = tts[uuc][bbc];
            const float* opb = ops + bbc * OSTR + uuc;
#pragma unroll 8
            for (int p = 0; p < PLEN; p++)
                acc += scst[bbc][p] * opb[p * 16];
            astore64(rwr + (size_t)(b0 + bbc) * 512 + u0 + uuc,
                     tpack(acc, TOFF + (unsigned)(3 * t + 3)));
        }
    }
}

// ---------------------------------------------------------------------------
// final: rep = tanh(r.fc1^T + b1 + hn.fc2^T + b2); out = rep.fc3^T + b3
__global__ __launch_bounds__(256) void final_kernel(
    const unsigned long long* __restrict__ r2, const float* __restrict__ outh,
    const float* __restrict__ fc1w, const float* __restrict__ fc1b,
    const float* __restrict__ fc2w, const float* __restrict__ fc2b,
    const float* __restrict__ fc3w, const float* __restrict__ fc3b,
    float* __restrict__ out)
{
    int b = blockIdx.x, tid = threadIdx.x;
    __shared__ float rs[HDIM], hs[HDIM], rep[HDIM], red[256];
    for (int i = tid; i < 512; i += 256)
        rs[i] = tval(r2[(size_t)b * 512 + i]);
    for (int i = tid; i < 128; i += 256)
        ((float4*)hs)[i] = ((const float4*)(outh + ((size_t)(b * HLEN + HLEN - 1)) * HDIM))[i];
    __syncthreads();
    for (int u = tid; u < HDIM; u += 256) {
        const float4* w1 = (const float4*)(fc1w + (size_t)u * HDIM);
        const float4* w2 = (const float4*)(fc2w + (size_t)u * HDIM);
        float a = 0.f, bacc = 0.f;
        for (int k = 0; k < 128; k++) {
            float4 rv = ((float4*)rs)[k], hv = ((float4*)hs)[k];
            float4 x = w1[k]; a    += rv.x * x.x + rv.y * x.y + rv.z * x.z + rv.w * x.w;
            float4 y = w2[k]; bacc += hv.x * y.x + hv.y * y.y + hv.z * y.z + hv.w * y.w;
        }
        rep[u] = tanhfast(a + fc1b[u] + bacc + fc2b[u]);
    }
    __syncthreads();
    for (int cix = 0; cix < NCLS; cix++) {
        red[tid] = rep[tid] * fc3w[(size_t)cix * HDIM + tid]
                 + rep[tid + 256] * fc3w[(size_t)cix * HDIM + tid + 256];
        __syncthreads();
        for (int off = 128; off; off >>= 1) {
            if (tid < off) red[tid] += red[tid + off];
            __syncthreads();
        }
        if (tid == 0) out[b * NCLS + cix] = red[0] + fc3b[cix];
        __syncthreads();
    }
}

// ---------------------------------------------------------------------------
extern "C" void kernel_launch(void* const* d_in, const int* in_sizes, int n_in,
                              void* d_out, int out_size, void* d_ws, size_t ws_size,
                              hipStream_t stream)
{
    const int*   premise = (const int*)d_in[0];
    const int*   hyp     = (const int*)d_in[1];
    const float* emb     = (const float*)d_in[2];
    const float* Wih1    = (const float*)d_in[3];
    const float* Whh1    = (const float*)d_in[4];
    const float* bih1    = (const float*)d_in[5];
    const float* bhh1    = (const float*)d_in[6];
    const float* Wih2    = (const float*)d_in[7];
    const float* Whh2    = (const float*)d_in[8];
    const float* bih2    = (const float*)d_in[9];
    const float* bhh2    = (const float*)d_in[10];
    const float* Wy      = (const float*)d_in[11];
    const float* Wh      = (const float*)d_in[12];
    const float* Wr      = (const float*)d_in[13];
    const float* Wt      = (const float*)d_in[14];
    const float* wv      = (const float*)d_in[15];
    const float* fc1w    = (const float*)d_in[16];
    const float* fc1b    = (const float*)d_in[17];
    const float* fc2w    = (const float*)d_in[18];
    const float* fc2b    = (const float*)d_in[19];
    const float* fc3w    = (const float*)d_in[20];
    const float* fc3b    = (const float*)d_in[21];
    float* out = (float*)d_out;

    float* ws = (float*)d_ws;
    size_t off = 0;
    float* xp    = ws + off; off += (size_t)BSZ * PLEN * G4;
    float* xh    = ws + off; off += (size_t)BSZ * HLEN * G4;
    float* outp  = ws + off; off += (size_t)BSZ * PLEN * HDIM;
    float* outhp = ws + off; off += (size_t)BSZ * HLEN * HDIM;
    float* a1b   = ws + off; off += (size_t)BSZ * HDIM * PLEN;   // [b][p][h]
    // tagged u64 exchange buffers (contiguous so one zero-kernel covers all).
    // lstm layer-2 h exchange reuses rA/rB (att tags are TOFF-offset).
    unsigned long long* tbase = (unsigned long long*)(ws + off);
    unsigned long long* hAb   = tbase;
    unsigned long long* hBb   = tbase + 32768;            // 64*512
    unsigned long long* a2buf = tbase + 2 * 32768;
    unsigned long long* rAb   = tbase + 3 * 32768;        // also lstm hC
    unsigned long long* rBb   = tbase + 4 * 32768;        // also lstm hD
    unsigned long long* sbuf  = tbase + 5 * 32768;        // 64*128
    off += (size_t)(5 * 32768 + 8192) * 2;                // in floats
    if (ws_size < off * sizeof(float)) return;

    // zero tagged buffers (172032 u64 = 672 * 256)
    ws_zero<<<dim3(672), dim3(256), 0, stream>>>(tbase);

    // input projections (biases folded in): 32x64 tiles
    proj_kernel<<<dim3(BSZ * PLEN / 32, G4 / 64), dim3(256), 0, stream>>>(
        premise, emb, Wih1, bih1, bhh1, xp);
    proj_kernel<<<dim3(BSZ * HLEN / 32, G4 / 64), dim3(256), 0, stream>>>(
        hyp, emb, Wih2, bih2, bhh2, xh);

    // both LSTMs, persistent, tagged-data sync (layer2 h via rA/rB)
    lstm_coop<<<dim3(256), dim3(256), 0, stream>>>(
        xp, xh, Whh1, Whh2, outp, outhp, hAb, hBb, rAb, rBb);

    // a1t = einsum('hj,bpj->bph', Wy, outp)
    a1_kernel<<<dim3(BSZ, PLEN / 32, HDIM / 64), dim3(256), 0, stream>>>(Wy, outp, a1b);

    // attention recurrence, persistent, tagged-data sync
    att_coop<<<dim3(256), dim3(256), 0, stream>>>(
        outhp, a1b, outp, Wh, Wr, Wt, wv, a2buf, sbuf, rAb, rBb);

    // final classifier: r after step 63 lives in rB (63 & 1 == 1)
    final_kernel<<<dim3(BSZ), dim3(256), 0, stream>>>(
        rBb, outhp, fc1w, fc1b, fc2w, fc2b, fc3w, fc3b, out);
}